// Round 10
// baseline (507.282 us; speedup 1.0000x reference)
//
#include <hip/hip_runtime.h>
#include <hip/hip_bf16.h>
#include <stdint.h>
#include <stddef.h>

typedef __bf16 bf16_t;
typedef __bf16 bf16x8 __attribute__((ext_vector_type(8)));
typedef __bf16 bf16x4 __attribute__((ext_vector_type(4)));
typedef float  f32x4  __attribute__((ext_vector_type(4)));

#define MFMA16(a, b, c) __builtin_amdgcn_mfma_f32_16x16x32_bf16((a), (b), (c), 0, 0, 0)

// SiLU with raw v_rcp_f32 (1-ulp; invisible after bf16 truncation).
__device__ __forceinline__ float silu_f(float v) {
    return v * __builtin_amdgcn_rcpf(1.f + __expf(-v));
}

// Raw-barrier phase end (T3/T4): drain ONLY LDS (write visibility), keep
// global prefetch loads in flight across the barrier. sched_barrier stops
// the scheduler hoisting next-phase ds ops above the barrier (rule #18).
#define PHASE_BAR() do {                                   \
    asm volatile("s_waitcnt lgkmcnt(0)" ::: "memory");     \
    __builtin_amdgcn_s_barrier();                          \
    __builtin_amdgcn_sched_barrier(0);                     \
} while (0)

namespace cfg {
constexpr int B    = 131072;
constexpr int DIM  = 40;
constexpr int H    = 128;
constexpr int AD   = 20;
constexpr int L    = 6;
constexpr int MB   = 64;     // rows per block
constexpr int NTH  = 256;    // threads per block (4 waves)
constexpr int ZS   = 41;     // z_s padded stride

// global weight tiles: [L][21][128][32] bf16 (linear).
// LDS weight tile: 128 cols x 6 slots of 16 B (96-B col rows) + slot-XOR:
// derived conflict-free for b0/b1 reads, SWRITE, and st reads (all 8
// 4-bank windows hit exactly 4x per half-wave).
constexpr int TILE  = 128 * 32;     // global tile elems
constexpr int LTILE = 128 * 48;     // LDS tile elems (6144 = 12288 B)
constexpr int LSTR  = 21 * TILE;
constexpr int WTOT  = 6 * LSTR;

constexpr int CTE_BLKS = B / 16;    // one block per 16-row group (coalesced prep)
constexpr int W_BLKS   = WTOT / 256;
}

__device__ __align__(16) bf16_t g_wsb[cfg::WTOT];
// slot tables: pa[6][32] (k 20..31 pad slot 0), pb[6][20], fout[40]
__device__ int    g_gtab[352];
// ctx|te bf16 swizzled [B/16][kt 8][lane 64][8]: lane's 16-B load IS its A-frag.
__device__ __align__(16) bf16_t g_cte[(size_t)cfg::B * 256];

// LDS weight-tile ELEMENT offset for (col an, 16-B k-slot s).
__device__ __forceinline__ int woff(int an, int s) {
    return an * 48 + ((s ^ ((an >> 1) & 3)) << 3);
}

// ---------------------------------------------------------------------------
// prep_all (identical to round 9; verified correct).
// ---------------------------------------------------------------------------
__global__ void prep_all(const float* __restrict__ ctx, const float* __restrict__ te,
                         const float* __restrict__ W1, const float* __restrict__ W2,
                         const float* __restrict__ W3, const float* __restrict__ Ws,
                         const float* __restrict__ Wt, const int* __restrict__ perm,
                         const int* __restrict__ ia, const int* __restrict__ ib)
{
    using namespace cfg;
    __shared__ int phys_s[40], tmp_s[40], pas[20], pbs[20];
    __shared__ bf16_t cb[16 * 264];

    if (blockIdx.x < CTE_BLKS) {
        int g16 = blockIdx.x;
        int t = threadIdx.x;
        #pragma unroll
        for (int k = 0; k < 4; ++k) {
            int f4 = k * 256 + t;
            int r = f4 >> 6, c4 = (f4 & 63) * 4;
            const float* src = (c4 < 128) ? &ctx[((size_t)g16 * 16 + r) * 128 + c4]
                                          : &te[((size_t)g16 * 16 + r) * 128 + (c4 - 128)];
            float4 v = *(const float4*)src;
            bf16x4 bv;
            bv[0] = (bf16_t)v.x; bv[1] = (bf16_t)v.y; bv[2] = (bf16_t)v.z; bv[3] = (bf16_t)v.w;
            *(bf16x4*)&cb[r * 264 + c4] = bv;
        }
        __syncthreads();
        #pragma unroll
        for (int kk = 0; kk < 2; ++kk) {
            int t2 = kk * 256 + t;
            int kt = t2 >> 6, ln = t2 & 63, q = ln >> 4, c = ln & 15;
            bf16x8 o = *(const bf16x8*)&cb[c * 264 + kt * 32 + q * 8];
            *(bf16x8*)&g_cte[(size_t)g16 * 4096 + (size_t)t2 * 8] = o;
        }
        return;
    }

    int bb = blockIdx.x - CTE_BLKS;
    int t  = bb * 256 + threadIdx.x;
    {
        int i = t / LSTR, r = t % LSTR;
        int tile = r / TILE, r2 = r % TILE;
        int n = r2 >> 5, kl = r2 & 31;
        float v = 0.f;
        if (tile < 9) {                      // W1: k-layout [za(20) pad12 | ctx | te]
            int k = tile * 32 + kl;
            if (k < 20)       v = W1[(i * 276 + k) * 128 + n];
            else if (k >= 32) v = W1[(i * 276 + (k - 12)) * 128 + n];
        } else if (tile < 13) {
            int k = (tile - 9) * 32 + kl;
            v = W2[(i * 128 + k) * 128 + n];
        } else if (tile < 17) {
            int k = (tile - 13) * 32 + kl;
            v = W3[(i * 128 + k) * 128 + n];
        } else {
            int k = (tile - 17) * 32 + kl;
            if (n < 20)                 v = Ws[(i * 128 + k) * 20 + n];
            else if (n >= 32 && n < 52) v = Wt[(i * 128 + k) * 20 + (n - 32)];
        }
        g_wsb[t] = (bf16_t)v;
    }

    if (bb == 0) {
        int u = threadIdx.x;
        if (u < 40) phys_s[u] = u;
        __syncthreads();
        for (int i = 0; i < L; ++i) {
            if (u < 20) {
                int sa = phys_s[perm[i * 40 + ia[i * 20 + u]]];
                int sb = phys_s[perm[i * 40 + ib[i * 20 + u]]];
                pas[u] = sa; pbs[u] = sb;
                g_gtab[i * 32 + u]        = sa;
                g_gtab[192 + i * 20 + u]  = sb;
            } else if (u < 32) {
                g_gtab[i * 32 + u] = 0;
            }
            __syncthreads();
            if (u < 20) {
                tmp_s[ia[i * 20 + u]] = pas[u];
                tmp_s[ib[i * 20 + u]] = pbs[u];
            }
            __syncthreads();
            if (u < 40) phys_s[u] = tmp_s[u];
            __syncthreads();
        }
        if (u < 40) g_gtab[312 + u] = phys_s[u];
    }
}

// ---------------------------------------------------------------------------
// flow_main: round-6 phase structure + (a) depth-2 weight prefetch (loads for
// tile T+2 issued at phase T; SWRITE's wait is satisfied a full phase early),
// (b) raw s_barrier with lgkmcnt-only drain (prefetch survives the barrier),
// (c) derived conflict-free 96-B-row wb layout. Per-layer pipeline restart
// keeps regset parity compile-time with a single body (no r7 duplication).
// ---------------------------------------------------------------------------
__global__ __launch_bounds__(256, 3) void flow_main(
    const float* __restrict__ x,
    const float* __restrict__ gb1, const float* __restrict__ gb2, const float* __restrict__ gb3,
    const float* __restrict__ gbs, const float* __restrict__ gbt,
    float* __restrict__ out)
{
    using namespace cfg;
    // LDS 53888 B -> 3 blocks/CU (54272 rounded x3 = 162816 <= 163840)
    __shared__ __align__(16) char smem[53888];
    float*  z_s  = (float*)(smem);             // [64][41] f32   @0      (10496 B)
    bf16_t* h    = (bf16_t*)(smem + 10496);    // [64][136] bf16 @10496  (17408 B)
    bf16_t* wb   = (bf16_t*)(smem + 27904);    // [2][128][48]   @27904  (24576 B)
    int*    gtab = (int*)(smem + 52480);       // 352 ints       @52480  (1408 B)

    const int tid  = threadIdx.x;
    const int lane = tid & 63;
    const int w    = tid >> 6;
    const int q    = lane >> 4, c = lane & 15;
    const int rw   = w * 16;                   // st row base
    const int cb   = w * 32 + 2 * c;           // dense-mm col-pair base
    const int row0 = blockIdx.x * MB;

    for (int e = tid; e < 352; e += NTH) gtab[e] = g_gtab[e];
    for (int e = tid; e < MB * DIM; e += NTH) {
        int r = e / DIM, d = e - r * DIM;
        z_s[r * ZS + d] = x[(size_t)row0 * DIM + e];
    }

    // depth-2 staging: two NAMED regset pairs, parity always a literal.
    uint4 sgA0, sgA1, sgB0, sgB1;
    const int an0 = tid >> 2, sl0 = tid & 3;
#define SLOADP(P, T) do { const bf16_t* _s = g_wsb + (size_t)(T) * cfg::TILE;              \
        if ((P) == 0) { sgA0 = *(const uint4*)(_s + (size_t)tid * 8);                      \
                        sgA1 = *(const uint4*)(_s + 2048 + (size_t)tid * 8); }             \
        else          { sgB0 = *(const uint4*)(_s + (size_t)tid * 8);                      \
                        sgB1 = *(const uint4*)(_s + 2048 + (size_t)tid * 8); } } while (0)
#define SWRITEP(P, wbc) do {                                                               \
        if ((P) == 0) { *(uint4*)&(wbc)[woff(an0, sl0)]      = sgA0;                       \
                        *(uint4*)&(wbc)[woff(an0 + 64, sl0)] = sgA1; }                     \
        else          { *(uint4*)&(wbc)[woff(an0, sl0)]      = sgB0;                       \
                        *(uint4*)&(wbc)[woff(an0 + 64, sl0)] = sgB1; } } while (0)

    float ld[4] = {0.f, 0.f, 0.f, 0.f};
    __syncthreads();                           // gtab/z_s ready (once; full drain OK)

    for (int i = 0; i < L; ++i) {
        const int* pa = gtab + i * 32;
        const int* pb = gtab + 192 + i * 20;
        const int  T0 = i * 21;

        // per-layer pipeline prologue: wb0 <- tile T0; B-set <- tile T0+1
        SLOADP(0, T0);
        SWRITEP(0, wb);                        // exposed wait, once per layer
        SLOADP(1, T0 + 1);
        PHASE_BAR();

        // ---- mm1: phases 0..8 (tiles T0..T0+8)
        {
            f32x4 acc[4][2] = {};
            bf16x8 aN[4];
            #pragma unroll
            for (int pl = 0; pl < 9; ++pl) {
                const int S = pl & 1;
                bf16_t* wbc = wb + S * LTILE;
                SLOADP(S, T0 + pl + 2);        // consumed at phase pl+1's SWRITE
                bf16x8 aK[4];
                if (pl == 0) {
                    #pragma unroll
                    for (int rf = 0; rf < 4; ++rf) {
                        bf16x8 t;
                        #pragma unroll
                        for (int j = 0; j < 8; ++j)
                            t[j] = (bf16_t)z_s[(rf * 16 + c) * ZS + pa[q * 8 + j]];
                        aK[rf] = t;
                    }
                    #pragma unroll
                    for (int rf = 0; rf < 4; ++rf)
                        aN[rf] = *(const bf16x8*)&g_cte[((size_t)(blockIdx.x * 4 + rf)) * 4096 + lane * 8];
                } else {
                    #pragma unroll
                    for (int rf = 0; rf < 4; ++rf) aK[rf] = aN[rf];
                    if (pl < 8) {
                        #pragma unroll
                        for (int rf = 0; rf < 4; ++rf)
                            aN[rf] = *(const bf16x8*)&g_cte[((size_t)(blockIdx.x * 4 + rf)) * 4096 + (size_t)pl * 512 + lane * 8];
                    }
                }
                bf16x8 b0 = *(const bf16x8*)&wbc[woff(cb, q)];
                bf16x8 b1 = *(const bf16x8*)&wbc[woff(cb + 1, q)];
                __builtin_amdgcn_s_setprio(1);
                #pragma unroll
                for (int rf = 0; rf < 4; ++rf) {
                    acc[rf][0] = MFMA16(aK[rf], b0, acc[rf][0]);
                    acc[rf][1] = MFMA16(aK[rf], b1, acc[rf][1]);
                }
                __builtin_amdgcn_s_setprio(0);
                if (pl == 8) {                 // SiLU epilogue -> h
                    float bv0 = gb1[i * H + cb], bv1 = gb1[i * H + cb + 1];
                    #pragma unroll
                    for (int rf = 0; rf < 4; ++rf)
                        #pragma unroll
                        for (int rr = 0; rr < 4; ++rr) {
                            float v0 = silu_f(acc[rf][0][rr] + bv0);
                            float v1 = silu_f(acc[rf][1][rr] + bv1);
                            union { bf16_t h2[2]; uint32_t u; } pk;
                            pk.h2[0] = (bf16_t)v0; pk.h2[1] = (bf16_t)v1;
                            *(uint32_t*)&h[(rf * 16 + q * 4 + rr) * 136 + cb] = pk.u;
                        }
                }
                SWRITEP(S ^ 1, wb + (S ^ 1) * LTILE);   // tile T0+pl+1, loaded last phase
                PHASE_BAR();
            }
        }

        // ---- mm2 (phases 9..12), mm3 (13..16): in-place h, hoisted A
        #pragma unroll
        for (int mm = 0; mm < 2; ++mm) {
            bf16x8 ah[16];
            #pragma unroll
            for (int kt = 0; kt < 4; ++kt)
                #pragma unroll
                for (int rf = 0; rf < 4; ++rf)
                    ah[kt * 4 + rf] = *(const bf16x8*)&h[(rf * 16 + c) * 136 + kt * 32 + q * 8];
            f32x4 acc[4][2] = {};
            const float* bias = (mm == 0 ? gb2 : gb3) + i * H;
            #pragma unroll
            for (int kt = 0; kt < 4; ++kt) {
                const int pl = 9 + mm * 4 + kt;
                const int S = pl & 1;
                bf16_t* wbc = wb + S * LTILE;
                SLOADP(S, T0 + pl + 2);
                bf16x8 b0 = *(const bf16x8*)&wbc[woff(cb, q)];
                bf16x8 b1 = *(const bf16x8*)&wbc[woff(cb + 1, q)];
                __builtin_amdgcn_s_setprio(1);
                #pragma unroll
                for (int rf = 0; rf < 4; ++rf) {
                    acc[rf][0] = MFMA16(ah[kt * 4 + rf], b0, acc[rf][0]);
                    acc[rf][1] = MFMA16(ah[kt * 4 + rf], b1, acc[rf][1]);
                }
                __builtin_amdgcn_s_setprio(0);
                if (kt == 3) {
                    float bv0 = bias[cb], bv1 = bias[cb + 1];
                    #pragma unroll
                    for (int rf = 0; rf < 4; ++rf)
                        #pragma unroll
                        for (int rr = 0; rr < 4; ++rr) {
                            float v0 = silu_f(acc[rf][0][rr] + bv0);
                            float v1 = silu_f(acc[rf][1][rr] + bv1);
                            union { bf16_t h2[2]; uint32_t u; } pk;
                            pk.h2[0] = (bf16_t)v0; pk.h2[1] = (bf16_t)v1;
                            *(uint32_t*)&h[(rf * 16 + q * 4 + rr) * 136 + cb] = pk.u;
                        }
                }
                SWRITEP(S ^ 1, wb + (S ^ 1) * LTILE);
                PHASE_BAR();
            }
        }

        // ---- st (phases 17..20) + fused epilogue (wave-private 16 rows)
        {
            f32x4 sacc[4] = {};
            #pragma unroll
            for (int kt = 0; kt < 4; ++kt) {
                const int pl = 17 + kt;
                const int S = pl & 1;
                bf16_t* wbc = wb + S * LTILE;
                if (pl <= 18) SLOADP(S, T0 + pl + 2);
                bf16x8 af = *(const bf16x8*)&h[(rw + c) * 136 + kt * 32 + q * 8];
                __builtin_amdgcn_s_setprio(1);
                #pragma unroll
                for (int nt = 0; nt < 4; ++nt) {
                    bf16x8 bfr = *(const bf16x8*)&wbc[woff(nt * 16 + c, q)];
                    sacc[nt] = MFMA16(af, bfr, sacc[nt]);
                }
                __builtin_amdgcn_s_setprio(0);
                if (kt == 3) {
                    float bs0 = gbs[i * AD + c];
                    float bt0 = gbt[i * AD + c];
                    int   sl1 = pb[c];
                    float bs1 = 0.f, bt1 = 0.f; int sl2 = 0;
                    if (c < 4) { bs1 = gbs[i * AD + 16 + c]; bt1 = gbt[i * AD + 16 + c]; sl2 = pb[16 + c]; }
                    #pragma unroll
                    for (int rr = 0; rr < 4; ++rr) {
                        int row = rw + q * 4 + rr;
                        float s1 = fminf(fmaxf(sacc[0][rr] + bs0, -2.f), 2.f);
                        float y1 = z_s[row * ZS + sl1] * __expf(s1) + (sacc[2][rr] + bt0);
                        z_s[row * ZS + sl1] = y1;
                        float ssum = s1;
                        if (c < 4) {
                            float s2 = fminf(fmaxf(sacc[1][rr] + bs1, -2.f), 2.f);
                            float y2 = z_s[row * ZS + sl2] * __expf(s2) + (sacc[3][rr] + bt1);
                            z_s[row * ZS + sl2] = y2;
                            ssum += s2;
                        }
                        ssum += __shfl_xor(ssum, 1);
                        ssum += __shfl_xor(ssum, 2);
                        ssum += __shfl_xor(ssum, 4);
                        ssum += __shfl_xor(ssum, 8);
                        ld[rr] += ssum;
                    }
                }
                if (pl <= 19) SWRITEP(S ^ 1, wb + (S ^ 1) * LTILE);
                PHASE_BAR();
            }
        }
    }

    // out gather through the final physical-slot map.
    const int* fo = gtab + 312;
    for (int e = tid; e < MB * DIM; e += NTH) {
        int r = e / DIM, d = e - r * DIM;
        out[(size_t)row0 * DIM + e] = z_s[r * ZS + fo[d]];
    }
    if (c == 0) {
        #pragma unroll
        for (int rr = 0; rr < 4; ++rr)
            out[(size_t)B * DIM + row0 + rw + q * 4 + rr] = ld[rr];
    }
#undef SLOADP
#undef SWRITEP
}

extern "C" void kernel_launch(void* const* d_in, const int* in_sizes, int n_in,
                              void* d_out, int out_size, void* d_ws, size_t ws_size,
                              hipStream_t stream) {
    using namespace cfg;
    const float* x   = (const float*)d_in[0];
    const float* ctx = (const float*)d_in[1];
    const float* te  = (const float*)d_in[2];
    const float* W1  = (const float*)d_in[3];
    const float* b1  = (const float*)d_in[4];
    const float* W2  = (const float*)d_in[5];
    const float* b2  = (const float*)d_in[6];
    const float* W3  = (const float*)d_in[7];
    const float* b3  = (const float*)d_in[8];
    const float* Ws_ = (const float*)d_in[9];
    const float* bs_ = (const float*)d_in[10];
    const float* Wt_ = (const float*)d_in[11];
    const float* bt_ = (const float*)d_in[12];
    const int* perm  = (const int*)d_in[13];
    const int* ia    = (const int*)d_in[14];
    const int* ib    = (const int*)d_in[15];

    float* out = (float*)d_out;

    prep_all<<<CTE_BLKS + W_BLKS, 256, 0, stream>>>(ctx, te, W1, W2, W3, Ws_, Wt_, perm, ia, ib);
    flow_main<<<B / MB, NTH, 0, stream>>>(x, b1, b2, b3, bs_, bt_, out);
}

// Round 11
// 454.284 us; speedup vs baseline: 1.1167x; 1.1167x over previous
//
#include <hip/hip_runtime.h>
#include <hip/hip_bf16.h>
#include <stdint.h>
#include <stddef.h>

typedef __bf16 bf16_t;
typedef __bf16 bf16x8 __attribute__((ext_vector_type(8)));
typedef __bf16 bf16x4 __attribute__((ext_vector_type(4)));
typedef float  f32x4  __attribute__((ext_vector_type(4)));

#define MFMA16(a, b, c) __builtin_amdgcn_mfma_f32_16x16x32_bf16((a), (b), (c), 0, 0, 0)

// SiLU with raw v_rcp_f32 (1-ulp; invisible after bf16 truncation).
__device__ __forceinline__ float silu_f(float v) {
    return v * __builtin_amdgcn_rcpf(1.f + __expf(-v));
}

// Raw-barrier phase end (T3/T4): drain ONLY LDS (write visibility), keep
// global prefetch loads in flight across the barrier. sched_barrier stops
// the scheduler moving ds ops across the barrier (rule #18).
#define PHASE_BAR() do {                                   \
    asm volatile("s_waitcnt lgkmcnt(0)" ::: "memory");     \
    __builtin_amdgcn_s_barrier();                          \
    __builtin_amdgcn_sched_barrier(0);                     \
} while (0)

namespace cfg {
constexpr int B    = 131072;
constexpr int DIM  = 40;
constexpr int H    = 128;
constexpr int AD   = 20;
constexpr int L    = 6;
constexpr int MB   = 64;     // rows per block
constexpr int NTH  = 256;    // threads per block (4 waves)
constexpr int ZS   = 41;     // z_s padded stride

// global weight tiles: [L][21][128][32] bf16 (linear).
// LDS weight tile: [128][32] (64-B rows) + 4-slot XOR — the measured-best
// layout (r6: 17.7M conflict cyc vs 40.5M/37.4M for 80/96-B variants).
constexpr int TILE  = 128 * 32;     // global tile elems
constexpr int LTILE = 128 * 32;     // LDS tile elems (8192 B)
constexpr int LSTR  = 21 * TILE;
constexpr int WTOT  = 6 * LSTR;

constexpr int CTE_BLKS = B / 16;    // one block per 16-row group (coalesced prep)
constexpr int W_BLKS   = WTOT / 256;
}

__device__ __align__(16) bf16_t g_wsb[cfg::WTOT];
// slot tables: pa[6][32] (k 20..31 pad slot 0), pb[6][20], fout[40]
__device__ int    g_gtab[352];
// ctx|te bf16 swizzled [B/16][kt 8][lane 64][8]: lane's 16-B load IS its A-frag.
__device__ __align__(16) bf16_t g_cte[(size_t)cfg::B * 256];

// LDS weight-tile ELEMENT offset for (col an, 16-B k-slot s).
__device__ __forceinline__ int woff(int an, int s) {
    return an * 32 + (((s ^ (an >> 1)) & 3) << 3);
}

// ---------------------------------------------------------------------------
// prep_all (identical to round 9/10; verified correct).
// ---------------------------------------------------------------------------
__global__ void prep_all(const float* __restrict__ ctx, const float* __restrict__ te,
                         const float* __restrict__ W1, const float* __restrict__ W2,
                         const float* __restrict__ W3, const float* __restrict__ Ws,
                         const float* __restrict__ Wt, const int* __restrict__ perm,
                         const int* __restrict__ ia, const int* __restrict__ ib)
{
    using namespace cfg;
    __shared__ int phys_s[40], tmp_s[40], pas[20], pbs[20];
    __shared__ bf16_t cb[16 * 264];

    if (blockIdx.x < CTE_BLKS) {
        int g16 = blockIdx.x;
        int t = threadIdx.x;
        #pragma unroll
        for (int k = 0; k < 4; ++k) {
            int f4 = k * 256 + t;
            int r = f4 >> 6, c4 = (f4 & 63) * 4;
            const float* src = (c4 < 128) ? &ctx[((size_t)g16 * 16 + r) * 128 + c4]
                                          : &te[((size_t)g16 * 16 + r) * 128 + (c4 - 128)];
            float4 v = *(const float4*)src;
            bf16x4 bv;
            bv[0] = (bf16_t)v.x; bv[1] = (bf16_t)v.y; bv[2] = (bf16_t)v.z; bv[3] = (bf16_t)v.w;
            *(bf16x4*)&cb[r * 264 + c4] = bv;
        }
        __syncthreads();
        #pragma unroll
        for (int kk = 0; kk < 2; ++kk) {
            int t2 = kk * 256 + t;
            int kt = t2 >> 6, ln = t2 & 63, q = ln >> 4, c = ln & 15;
            bf16x8 o = *(const bf16x8*)&cb[c * 264 + kt * 32 + q * 8];
            *(bf16x8*)&g_cte[(size_t)g16 * 4096 + (size_t)t2 * 8] = o;
        }
        return;
    }

    int bb = blockIdx.x - CTE_BLKS;
    int t  = bb * 256 + threadIdx.x;
    {
        int i = t / LSTR, r = t % LSTR;
        int tile = r / TILE, r2 = r % TILE;
        int n = r2 >> 5, kl = r2 & 31;
        float v = 0.f;
        if (tile < 9) {                      // W1: k-layout [za(20) pad12 | ctx | te]
            int k = tile * 32 + kl;
            if (k < 20)       v = W1[(i * 276 + k) * 128 + n];
            else if (k >= 32) v = W1[(i * 276 + (k - 12)) * 128 + n];
        } else if (tile < 13) {
            int k = (tile - 9) * 32 + kl;
            v = W2[(i * 128 + k) * 128 + n];
        } else if (tile < 17) {
            int k = (tile - 13) * 32 + kl;
            v = W3[(i * 128 + k) * 128 + n];
        } else {
            int k = (tile - 17) * 32 + kl;
            if (n < 20)                 v = Ws[(i * 128 + k) * 20 + n];
            else if (n >= 32 && n < 52) v = Wt[(i * 128 + k) * 20 + (n - 32)];
        }
        g_wsb[t] = (bf16_t)v;
    }

    if (bb == 0) {
        int u = threadIdx.x;
        if (u < 40) phys_s[u] = u;
        __syncthreads();
        for (int i = 0; i < L; ++i) {
            if (u < 20) {
                int sa = phys_s[perm[i * 40 + ia[i * 20 + u]]];
                int sb = phys_s[perm[i * 40 + ib[i * 20 + u]]];
                pas[u] = sa; pbs[u] = sb;
                g_gtab[i * 32 + u]        = sa;
                g_gtab[192 + i * 20 + u]  = sb;
            } else if (u < 32) {
                g_gtab[i * 32 + u] = 0;
            }
            __syncthreads();
            if (u < 20) {
                tmp_s[ia[i * 20 + u]] = pas[u];
                tmp_s[ib[i * 20 + u]] = pbs[u];
            }
            __syncthreads();
            if (u < 40) phys_s[u] = tmp_s[u];
            __syncthreads();
        }
        if (u < 40) g_gtab[312 + u] = phys_s[u];
    }
}

// ---------------------------------------------------------------------------
// flow_main: r6 phase structure + wb layout (measured-best), with r10's
// depth-2 weight prefetch (loads for tile T+2 issued at phase T) and raw
// s_barrier with lgkmcnt-only drain (prefetch survives the barrier).
// Per-layer pipeline restart keeps regset parity compile-time.
// ---------------------------------------------------------------------------
__global__ __launch_bounds__(256, 3) void flow_main(
    const float* __restrict__ x,
    const float* __restrict__ gb1, const float* __restrict__ gb2, const float* __restrict__ gb3,
    const float* __restrict__ gbs, const float* __restrict__ gbt,
    float* __restrict__ out)
{
    using namespace cfg;
    // LDS 45696 B -> 3 blocks/CU with margin
    __shared__ __align__(16) char smem[45696];
    float*  z_s  = (float*)(smem);             // [64][41] f32   @0      (10496 B)
    bf16_t* h    = (bf16_t*)(smem + 10496);    // [64][136] bf16 @10496  (17408 B)
    bf16_t* wb   = (bf16_t*)(smem + 27904);    // [2][128][32]   @27904  (16384 B)
    int*    gtab = (int*)(smem + 44288);       // 352 ints       @44288  (1408 B)

    const int tid  = threadIdx.x;
    const int lane = tid & 63;
    const int w    = tid >> 6;
    const int q    = lane >> 4, c = lane & 15;
    const int rw   = w * 16;                   // st row base
    const int cb   = w * 32 + 2 * c;           // dense-mm col-pair base
    const int row0 = blockIdx.x * MB;

    for (int e = tid; e < 352; e += NTH) gtab[e] = g_gtab[e];
    for (int e = tid; e < MB * DIM; e += NTH) {
        int r = e / DIM, d = e - r * DIM;
        z_s[r * ZS + d] = x[(size_t)row0 * DIM + e];
    }

    // depth-2 staging: two NAMED regset pairs, parity always a literal.
    uint4 sgA0, sgA1, sgB0, sgB1;
    const int an0 = tid >> 2, sl0 = tid & 3;
#define SLOADP(P, T) do { const bf16_t* _s = g_wsb + (size_t)(T) * cfg::TILE;              \
        if ((P) == 0) { sgA0 = *(const uint4*)(_s + (size_t)tid * 8);                      \
                        sgA1 = *(const uint4*)(_s + 2048 + (size_t)tid * 8); }             \
        else          { sgB0 = *(const uint4*)(_s + (size_t)tid * 8);                      \
                        sgB1 = *(const uint4*)(_s + 2048 + (size_t)tid * 8); } } while (0)
#define SWRITEP(P, wbc) do {                                                               \
        if ((P) == 0) { *(uint4*)&(wbc)[woff(an0, sl0)]      = sgA0;                       \
                        *(uint4*)&(wbc)[woff(an0 + 64, sl0)] = sgA1; }                     \
        else          { *(uint4*)&(wbc)[woff(an0, sl0)]      = sgB0;                       \
                        *(uint4*)&(wbc)[woff(an0 + 64, sl0)] = sgB1; } } while (0)

    float ld[4] = {0.f, 0.f, 0.f, 0.f};
    __syncthreads();                           // gtab/z_s ready (once; full drain OK)

    for (int i = 0; i < L; ++i) {
        const int* pa = gtab + i * 32;
        const int* pb = gtab + 192 + i * 20;
        const int  T0 = i * 21;

        // per-layer pipeline prologue: wb0 <- tile T0; B-set <- tile T0+1
        SLOADP(0, T0);
        SWRITEP(0, wb);                        // exposed wait, once per layer
        SLOADP(1, T0 + 1);
        PHASE_BAR();

        // ---- mm1: phases 0..8 (tiles T0..T0+8)
        {
            f32x4 acc[4][2] = {};
            bf16x8 aN[4];
            #pragma unroll
            for (int pl = 0; pl < 9; ++pl) {
                const int S = pl & 1;
                bf16_t* wbc = wb + S * LTILE;
                SLOADP(S, T0 + pl + 2);        // consumed at phase pl+1's SWRITE
                bf16x8 aK[4];
                if (pl == 0) {
                    #pragma unroll
                    for (int rf = 0; rf < 4; ++rf) {
                        bf16x8 t;
                        #pragma unroll
                        for (int j = 0; j < 8; ++j)
                            t[j] = (bf16_t)z_s[(rf * 16 + c) * ZS + pa[q * 8 + j]];
                        aK[rf] = t;
                    }
                    #pragma unroll
                    for (int rf = 0; rf < 4; ++rf)
                        aN[rf] = *(const bf16x8*)&g_cte[((size_t)(blockIdx.x * 4 + rf)) * 4096 + lane * 8];
                } else {
                    #pragma unroll
                    for (int rf = 0; rf < 4; ++rf) aK[rf] = aN[rf];
                    if (pl < 8) {
                        #pragma unroll
                        for (int rf = 0; rf < 4; ++rf)
                            aN[rf] = *(const bf16x8*)&g_cte[((size_t)(blockIdx.x * 4 + rf)) * 4096 + (size_t)pl * 512 + lane * 8];
                    }
                }
                bf16x8 b0 = *(const bf16x8*)&wbc[woff(cb, q)];
                bf16x8 b1 = *(const bf16x8*)&wbc[woff(cb + 1, q)];
                __builtin_amdgcn_s_setprio(1);
                #pragma unroll
                for (int rf = 0; rf < 4; ++rf) {
                    acc[rf][0] = MFMA16(aK[rf], b0, acc[rf][0]);
                    acc[rf][1] = MFMA16(aK[rf], b1, acc[rf][1]);
                }
                __builtin_amdgcn_s_setprio(0);
                if (pl == 8) {                 // SiLU epilogue -> h
                    float bv0 = gb1[i * H + cb], bv1 = gb1[i * H + cb + 1];
                    #pragma unroll
                    for (int rf = 0; rf < 4; ++rf)
                        #pragma unroll
                        for (int rr = 0; rr < 4; ++rr) {
                            float v0 = silu_f(acc[rf][0][rr] + bv0);
                            float v1 = silu_f(acc[rf][1][rr] + bv1);
                            union { bf16_t h2[2]; uint32_t u; } pk;
                            pk.h2[0] = (bf16_t)v0; pk.h2[1] = (bf16_t)v1;
                            *(uint32_t*)&h[(rf * 16 + q * 4 + rr) * 136 + cb] = pk.u;
                        }
                }
                SWRITEP(S ^ 1, wb + (S ^ 1) * LTILE);   // tile T0+pl+1, loaded last phase
                PHASE_BAR();
            }
        }

        // ---- mm2 (phases 9..12), mm3 (13..16): in-place h, hoisted A
        #pragma unroll
        for (int mm = 0; mm < 2; ++mm) {
            bf16x8 ah[16];
            #pragma unroll
            for (int kt = 0; kt < 4; ++kt)
                #pragma unroll
                for (int rf = 0; rf < 4; ++rf)
                    ah[kt * 4 + rf] = *(const bf16x8*)&h[(rf * 16 + c) * 136 + kt * 32 + q * 8];
            f32x4 acc[4][2] = {};
            const float* bias = (mm == 0 ? gb2 : gb3) + i * H;
            #pragma unroll
            for (int kt = 0; kt < 4; ++kt) {
                const int pl = 9 + mm * 4 + kt;
                const int S = pl & 1;
                bf16_t* wbc = wb + S * LTILE;
                SLOADP(S, T0 + pl + 2);
                bf16x8 b0 = *(const bf16x8*)&wbc[woff(cb, q)];
                bf16x8 b1 = *(const bf16x8*)&wbc[woff(cb + 1, q)];
                __builtin_amdgcn_s_setprio(1);
                #pragma unroll
                for (int rf = 0; rf < 4; ++rf) {
                    acc[rf][0] = MFMA16(ah[kt * 4 + rf], b0, acc[rf][0]);
                    acc[rf][1] = MFMA16(ah[kt * 4 + rf], b1, acc[rf][1]);
                }
                __builtin_amdgcn_s_setprio(0);
                if (kt == 3) {
                    float bv0 = bias[cb], bv1 = bias[cb + 1];
                    #pragma unroll
                    for (int rf = 0; rf < 4; ++rf)
                        #pragma unroll
                        for (int rr = 0; rr < 4; ++rr) {
                            float v0 = silu_f(acc[rf][0][rr] + bv0);
                            float v1 = silu_f(acc[rf][1][rr] + bv1);
                            union { bf16_t h2[2]; uint32_t u; } pk;
                            pk.h2[0] = (bf16_t)v0; pk.h2[1] = (bf16_t)v1;
                            *(uint32_t*)&h[(rf * 16 + q * 4 + rr) * 136 + cb] = pk.u;
                        }
                }
                SWRITEP(S ^ 1, wb + (S ^ 1) * LTILE);
                PHASE_BAR();
            }
        }

        // ---- st (phases 17..20) + fused epilogue (wave-private 16 rows)
        {
            f32x4 sacc[4] = {};
            #pragma unroll
            for (int kt = 0; kt < 4; ++kt) {
                const int pl = 17 + kt;
                const int S = pl & 1;
                bf16_t* wbc = wb + S * LTILE;
                if (pl <= 18) SLOADP(S, T0 + pl + 2);
                bf16x8 af = *(const bf16x8*)&h[(rw + c) * 136 + kt * 32 + q * 8];
                __builtin_amdgcn_s_setprio(1);
                #pragma unroll
                for (int nt = 0; nt < 4; ++nt) {
                    bf16x8 bfr = *(const bf16x8*)&wbc[woff(nt * 16 + c, q)];
                    sacc[nt] = MFMA16(af, bfr, sacc[nt]);
                }
                __builtin_amdgcn_s_setprio(0);
                if (kt == 3) {
                    float bs0 = gbs[i * AD + c];
                    float bt0 = gbt[i * AD + c];
                    int   sl1 = pb[c];
                    float bs1 = 0.f, bt1 = 0.f; int sl2 = 0;
                    if (c < 4) { bs1 = gbs[i * AD + 16 + c]; bt1 = gbt[i * AD + 16 + c]; sl2 = pb[16 + c]; }
                    #pragma unroll
                    for (int rr = 0; rr < 4; ++rr) {
                        int row = rw + q * 4 + rr;
                        float s1 = fminf(fmaxf(sacc[0][rr] + bs0, -2.f), 2.f);
                        float y1 = z_s[row * ZS + sl1] * __expf(s1) + (sacc[2][rr] + bt0);
                        z_s[row * ZS + sl1] = y1;
                        float ssum = s1;
                        if (c < 4) {
                            float s2 = fminf(fmaxf(sacc[1][rr] + bs1, -2.f), 2.f);
                            float y2 = z_s[row * ZS + sl2] * __expf(s2) + (sacc[3][rr] + bt1);
                            z_s[row * ZS + sl2] = y2;
                            ssum += s2;
                        }
                        ssum += __shfl_xor(ssum, 1);
                        ssum += __shfl_xor(ssum, 2);
                        ssum += __shfl_xor(ssum, 4);
                        ssum += __shfl_xor(ssum, 8);
                        ld[rr] += ssum;
                    }
                }
                if (pl <= 19) SWRITEP(S ^ 1, wb + (S ^ 1) * LTILE);
                PHASE_BAR();
            }
        }
    }

    // out gather through the final physical-slot map.
    const int* fo = gtab + 312;
    for (int e = tid; e < MB * DIM; e += NTH) {
        int r = e / DIM, d = e - r * DIM;
        out[(size_t)row0 * DIM + e] = z_s[r * ZS + fo[d]];
    }
    if (c == 0) {
        #pragma unroll
        for (int rr = 0; rr < 4; ++rr)
            out[(size_t)B * DIM + row0 + rw + q * 4 + rr] = ld[rr];
    }
#undef SLOADP
#undef SWRITEP
}

extern "C" void kernel_launch(void* const* d_in, const int* in_sizes, int n_in,
                              void* d_out, int out_size, void* d_ws, size_t ws_size,
                              hipStream_t stream) {
    using namespace cfg;
    const float* x   = (const float*)d_in[0];
    const float* ctx = (const float*)d_in[1];
    const float* te  = (const float*)d_in[2];
    const float* W1  = (const float*)d_in[3];
    const float* b1  = (const float*)d_in[4];
    const float* W2  = (const float*)d_in[5];
    const float* b2  = (const float*)d_in[6];
    const float* W3  = (const float*)d_in[7];
    const float* b3  = (const float*)d_in[8];
    const float* Ws_ = (const float*)d_in[9];
    const float* bs_ = (const float*)d_in[10];
    const float* Wt_ = (const float*)d_in[11];
    const float* bt_ = (const float*)d_in[12];
    const int* perm  = (const int*)d_in[13];
    const int* ia    = (const int*)d_in[14];
    const int* ib    = (const int*)d_in[15];

    float* out = (float*)d_out;

    prep_all<<<CTE_BLKS + W_BLKS, 256, 0, stream>>>(ctx, te, W1, W2, W3, Ws_, Wt_, perm, ia, ib);
    flow_main<<<B / MB, NTH, 0, stream>>>(x, b1, b2, b3, bs_, bt_, out);
}